// Round 6
// baseline (191.624 us; speedup 1.0000x reference)
//
#include <hip/hip_runtime.h>

typedef _Float16 half8 __attribute__((ext_vector_type(8)));
typedef float floatx4 __attribute__((ext_vector_type(4)));
typedef float float4v __attribute__((ext_vector_type(4)));

#define AUNITS (64 * 13 * 24 * 64)    // 16B units in A'' (fragment-tiled image)
#define TUNITS (64 * 4 * 24 * 64)     // 16B units in B'' (fragment-tiled text)
#define A_HALFS ((size_t)AUNITS * 8)
#define BJ_HALFS (24 * 4 * 64 * 8)    // 49152 halfs per j
#define AI_HALFS (13 * 24 * 512)      // 159744 halfs per i

__device__ __forceinline__ void gl_lds16(const _Float16* g, _Float16* l) {
  __builtin_amdgcn_global_load_lds(
      (const __attribute__((address_space(1))) unsigned int*)g,
      (__attribute__((address_space(3))) unsigned int*)l, 16, 0, 0);
}

// ---------- repack: f32 -> f16 into MFMA-fragment-tiled layout ----------
// A''[i][tau][s][lane]{8}: lane l holds A_i[n=tau*16+(l&15)][d=s*32+(l>>4)*8..+7]
// B''[j][s][ct][lane]{8}:  lane l holds B_j[m=ct*16+(l&15)][d=s*32+(l>>4)*8..+7]
__global__ __launch_bounds__(256) void repack(const float* __restrict__ img,
                                              const float* __restrict__ txt,
                                              _Float16* __restrict__ Apk,
                                              _Float16* __restrict__ Bpk) {
  int gid = blockIdx.x * 256 + threadIdx.x;
  const float* src;
  _Float16* dst;
  if (gid < AUNITS) {
    int l = gid & 63, g = gid >> 6;
    int s = g % 24; g /= 24;
    int tau = g % 13; int i = g / 13;
    int n = tau * 16 + (l & 15); if (n > 195) n = 195;   // dup-pad rows 196..207
    src = img + (size_t)i * 197 * 768 + (size_t)(n + 1) * 768 + s * 32 + (l >> 4) * 8;
    dst = Apk + (size_t)gid * 8;
  } else {
    int u = gid - AUNITS;
    int l = u & 63, g = u >> 6;
    int ct = g & 3; g >>= 2;
    int s = g % 24; int j = g / 24;
    int m = ct * 16 + (l & 15);
    src = txt + (size_t)j * 65 * 768 + (size_t)(m + 1) * 768 + s * 32 + (l >> 4) * 8;
    dst = Bpk + (size_t)u * 8;
  }
  float4v v0 = *(const float4v*)src;
  float4v v1 = *(const float4v*)(src + 4);
  half8 h;
  h[0] = (_Float16)v0[0]; h[1] = (_Float16)v0[1]; h[2] = (_Float16)v0[2]; h[3] = (_Float16)v0[3];
  h[4] = (_Float16)v1[0]; h[5] = (_Float16)v1[1]; h[6] = (_Float16)v1[2]; h[7] = (_Float16)v1[3];
  *(half8*)dst = h;
}

// ---------- per-(i, jb4): 208x256 block, 4 j's, 8 waves (512 thr) ----------
// Wave (wr,wc): wr=wave>>2 owns row-tiles [wr*7, wr*7+NT) (NT=7/6), wc=wave&3
// owns j = 4*jb4+wc.
// A: DMA-staged in LDS (shared by 8 waves), chunk = 2 K-steps, dbuf, ONE
//    barrier per chunk with COUNTED vmcnt(8) (8 B-loads are always newer than
//    the wave's last A-DMA; never vmcnt(0) mid-loop).
// B: global->register, depth-1 prefetch (issued before the MFMA cluster of the
//    previous step; L2 latency hides under ~540 cyc of MFMA). B'' is
//    L3-resident (6 MB) and per-XCD L2-hot (same jb4 set recurs across i).
// Pipes per K-step per CU: MFMA ~1048 cyc (floor), LDS ~830, L2 ~800.
__global__ __launch_bounds__(512, 2) void sim_kernel(const _Float16* __restrict__ Apk,
                                                     const _Float16* __restrict__ Bpk,
                                                     const int* __restrict__ pm,
                                                     const float* __restrict__ ls,
                                                     float* __restrict__ lpi,
                                                     float* __restrict__ lpt) {
  // LDS: A only. [buf2][sc2][tau13][512 halfs] = 26624 halfs = 53 KB
  __shared__ _Float16 LA[26624];

  const int jb4 = blockIdx.x, i = blockIdx.y;
  const int tid = threadIdx.x;
  const int wave = tid >> 6, lane = tid & 63;
  const int wr = wave >> 2, wc = wave & 3;
  const int NT = 7 - wr;                    // 7 row-tiles (wr0: 0..6) / 6 (wr1: 7..12)
  const int r16 = lane & 15;
  const int lane8 = lane * 8;

  const _Float16* Ag = Apk + (size_t)i * AI_HALFS;
  const _Float16* Bgw = Bpk + (size_t)(4 * jb4 + wc) * BJ_HALFS + lane8;

  // stage chunk cc of A (K-steps 2cc, 2cc+1) into buf cc&1.
  // 26 pieces (tau, sc) over 8 waves: waves 0,1 -> 4 pieces; waves 2..7 -> 3.
  auto stageA = [&](int cc) {
    const int buf = cc & 1;
#pragma unroll
    for (int k = 0; k < 4; ++k) {
      int p = wave + 8 * k;
      if (p < 26) {                         // wave-uniform branch
        int tau = p >> 1, sc = p & 1;
        gl_lds16(Ag + (size_t)(tau * 24 + 2 * cc + sc) * 512 + lane8,
                 LA + buf * 13312 + sc * 6656 + tau * 512);
      }
    }
  };

  floatx4 acc[7][4];
#pragma unroll
  for (int t = 0; t < 7; ++t)
#pragma unroll
    for (int n = 0; n < 4; ++n)
      acc[t][n] = (floatx4){0.f, 0.f, 0.f, 0.f};

  half8 a[2][7];
  half8 b[2][4];

  // prologue: stage chunk 0, load B(0); A landed when the 4 newer B-loads remain.
  stageA(0);
#pragma unroll
  for (int n = 0; n < 4; ++n) b[0][n] = *(const half8*)(Bgw + n * 512);
  __builtin_amdgcn_sched_barrier(0);
  asm volatile("s_waitcnt vmcnt(4)" ::: "memory");
  __builtin_amdgcn_s_barrier();
  __builtin_amdgcn_sched_barrier(0);

#pragma unroll
  for (int c = 0; c < 12; ++c) {
    const int buf = c & 1;

    // read BOTH K-steps' a-frags (14 ds_read_b128); MFMA(2c) starts after the
    // first 7 complete (compiler's counted lgkmcnt), rest fly underneath.
#pragma unroll
    for (int t = 0; t < 7; ++t)
      if (t < NT) {
        a[0][t] = *(const half8*)(LA + buf * 13312 +        (wr * 7 + t) * 512 + lane8);
        a[1][t] = *(const half8*)(LA + buf * 13312 + 6656 + (wr * 7 + t) * 512 + lane8);
      }

    if (c < 11) stageA(c + 1);              // A-DMA flies during this chunk's MFMAs

    // B for step 2c+1 (consumed after ~540 cyc of MFMA(2c))
#pragma unroll
    for (int n = 0; n < 4; ++n)
      b[1][n] = *(const half8*)(Bgw + (size_t)(2 * c + 1) * 2048 + n * 512);
    __builtin_amdgcn_sched_barrier(0);

    __builtin_amdgcn_s_setprio(1);
#pragma unroll
    for (int t = 0; t < 7; ++t)
      if (t < NT) {
#pragma unroll
        for (int n = 0; n < 4; ++n)
          acc[t][n] = __builtin_amdgcn_mfma_f32_16x16x32_f16(a[0][t], b[0][n], acc[t][n], 0, 0, 0);
      }
    __builtin_amdgcn_s_setprio(0);

    // B for step 2c+2 (next chunk's first step: global, no barrier dependency)
    if (c < 11) {
#pragma unroll
      for (int n = 0; n < 4; ++n)
        b[0][n] = *(const half8*)(Bgw + (size_t)(2 * c + 2) * 2048 + n * 512);
    }
    __builtin_amdgcn_sched_barrier(0);

    __builtin_amdgcn_s_setprio(1);
#pragma unroll
    for (int t = 0; t < 7; ++t)
      if (t < NT) {
#pragma unroll
        for (int n = 0; n < 4; ++n)
          acc[t][n] = __builtin_amdgcn_mfma_f32_16x16x32_f16(a[1][t], b[1][n], acc[t][n], 0, 0, 0);
      }
    __builtin_amdgcn_s_setprio(0);

    if (c < 11) {
      // chunk handoff: newer-than-last-A-DMA = 8 B-loads -> vmcnt(8) proves the
      // chunk-(c+1) DMA landed. Counted wait, then collective barrier.
      __builtin_amdgcn_sched_barrier(0);
      asm volatile("s_waitcnt vmcnt(8)" ::: "memory");
      __builtin_amdgcn_s_barrier();
      __builtin_amdgcn_sched_barrier(0);
    }
  }

  // ---------------- epilogue ----------------
  const float sgl = ls[0];
  int colc[4]; bool msk[4];
#pragma unroll
  for (int n = 0; n < 4; ++n) {
    colc[n] = n * 16 + r16;
    msk[n] = pm[i * 65 + 1 + colc[n]] != 0;
  }

  // rowsum: sum over VALID rows of (max over valid cols). Dup rows (196..207:
  // wr1 tile t==5 i.e. tau=12, lane>>4 != 0) excluded.
  float rowsum = 0.f;
#pragma unroll
  for (int t = 0; t < 7; ++t)
    if (t < NT) {
#pragma unroll
      for (int r = 0; r < 4; ++r) {
        float rm = -__builtin_inff();
#pragma unroll
        for (int n = 0; n < 4; ++n) {
          float v = acc[t][n][r] * sgl;
          rm = fmaxf(rm, msk[n] ? -__builtin_inff() : v);
        }
#pragma unroll
        for (int off = 1; off < 16; off <<= 1)
          rm = fmaxf(rm, __shfl_xor(rm, off, 64));
        bool vrow = (wr == 0) || (t < 5) || ((lane >> 4) == 0);
        rowsum += vrow ? rm : 0.f;
      }
    }
#pragma unroll
  for (int off = 1; off < 64; off <<= 1) rowsum += __shfl_xor(rowsum, off, 64);

  // per-column max over this wave's rows (unmasked; dup rows replicate row 195)
  float cm[4];
#pragma unroll
  for (int n = 0; n < 4; ++n) {
    float c = -__builtin_inff();
#pragma unroll
    for (int t = 0; t < 7; ++t)
      if (t < NT) {
#pragma unroll
        for (int r = 0; r < 4; ++r) c = fmaxf(c, acc[t][n][r] * sgl);
      }
    c = fmaxf(c, __shfl_xor(c, 16, 64));
    c = fmaxf(c, __shfl_xor(c, 32, 64));
    cm[n] = c;
  }

  __syncthreads();                          // full drain -> alias LA as scratch
  float* colmaxS = (float*)LA;              // [4 j][2 wr][64 col]
  float* wsumS   = (float*)LA + 512;        // [4 j][2 wr]

  if (lane < 16) {
#pragma unroll
    for (int n = 0; n < 4; ++n) colmaxS[(wc * 2 + wr) * 64 + colc[n]] = cm[n];
  }
  if (lane == 0) wsumS[wc * 2 + wr] = rowsum;
  __syncthreads();

  if (tid < 256) {                          // wave w -> j = w, lane = col
    const int j = wave, col = lane;
    bool valid = pm[i * 65 + 1 + col] == 0;
    float v = fmaxf(colmaxS[(j * 2 + 0) * 64 + col], colmaxS[(j * 2 + 1) * 64 + col]);
    float contrib = valid ? v : 0.f;
    float cntv = valid ? 1.f : 0.f;
#pragma unroll
    for (int off = 1; off < 64; off <<= 1) {
      contrib += __shfl_xor(contrib, off, 64);
      cntv += __shfl_xor(cntv, off, 64);
    }
    if (lane == 0) {
      int jout = 4 * jb4 + j;
      lpt[i * 64 + jout] = contrib / cntv;
      lpi[i * 64 + jout] = (wsumS[j * 2] + wsumS[j * 2 + 1]) * 0.0625f / 196.f;
    }
  }
}

// ---------------- CE losses + targets ----------------
// out layout: [0] loss | [1..4097) lpi | [4097..8193) lpt | [8193..8257) targets
__global__ __launch_bounds__(64) void ce_kernel(float* __restrict__ out) {
  const int t = threadIdx.x;
  const float* lpi = out + 1;
  const float* lpt = out + 1 + 4096;

  float mx = -__builtin_inff();
#pragma unroll
  for (int jj = 0; jj < 64; ++jj) mx = fmaxf(mx, lpi[t * 64 + jj]);
  float se = 0.f;
#pragma unroll
  for (int jj = 0; jj < 64; ++jj) se += __expf(lpi[t * 64 + jj] - mx);
  float ci = (mx + __logf(se)) - lpi[t * 64 + t];

  float mx2 = -__builtin_inff();
#pragma unroll
  for (int jj = 0; jj < 64; ++jj) mx2 = fmaxf(mx2, lpt[t * 64 + jj]);
  float se2 = 0.f;
#pragma unroll
  for (int jj = 0; jj < 64; ++jj) se2 += __expf(lpt[t * 64 + jj] - mx2);
  float ct_ = (mx2 + __logf(se2)) - lpt[t * 64 + t];

  float v = ci + ct_;
#pragma unroll
  for (int off = 1; off < 64; off <<= 1) v += __shfl_xor(v, off, 64);
  if (t == 0) out[0] = 0.5f * v / 64.f;
  out[1 + 8192 + t] = (float)t;   // targets = arange(64)
}

extern "C" void kernel_launch(void* const* d_in, const int* in_sizes, int n_in,
                              void* d_out, int out_size, void* d_ws, size_t ws_size,
                              hipStream_t stream) {
  const float* image = (const float*)d_in[0];   // (64,197,768) f32
  const float* text  = (const float*)d_in[1];   // (64,65,768) f32
  const int*   pm    = (const int*)d_in[2];     // (64,65) i32
  const float* ls    = (const float*)d_in[3];   // scalar
  float* out = (float*)d_out;

  _Float16* Apk = (_Float16*)d_ws;              // fragment-tiled image
  _Float16* Bpk = Apk + A_HALFS;                // fragment-tiled text

  repack<<<(AUNITS + TUNITS) / 256, 256, 0, stream>>>(image, text, Apk, Bpk);

  dim3 grid(16, 64);   // x = jb4 (fast): A_i stays L2-hot across consecutive blocks
  sim_kernel<<<grid, 512, 0, stream>>>(Apk, Bpk, pm, ls, out + 1, out + 1 + 4096);
  ce_kernel<<<1, 64, 0, stream>>>(out);
}

// Round 7
// 183.962 us; speedup vs baseline: 1.0416x; 1.0416x over previous
//
#include <hip/hip_runtime.h>

typedef _Float16 half8 __attribute__((ext_vector_type(8)));
typedef float floatx4 __attribute__((ext_vector_type(4)));
typedef float float4v __attribute__((ext_vector_type(4)));

#define AUNITS (64 * 13 * 24 * 64)    // 16B units in A'' (fragment-tiled image)
#define TUNITS (64 * 4 * 24 * 64)     // 16B units in B'' (fragment-tiled text)
#define A_HALFS ((size_t)AUNITS * 8)
#define BJ_HALFS (24 * 4 * 64 * 8)    // 49152 halfs per j
#define AI_HALFS (13 * 24 * 512)      // 159744 halfs per i

__device__ __forceinline__ void gl_lds16(const _Float16* g, _Float16* l) {
  __builtin_amdgcn_global_load_lds(
      (const __attribute__((address_space(1))) unsigned int*)g,
      (__attribute__((address_space(3))) unsigned int*)l, 16, 0, 0);
}

// ---------- repack: f32 -> f16 into MFMA-fragment-tiled layout ----------
// A''[i][tau][s][lane]{8}: lane l holds A_i[n=tau*16+(l&15)][d=s*32+(l>>4)*8..+7]
// B''[j][s][ct][lane]{8}:  lane l holds B_j[m=ct*16+(l&15)][d=s*32+(l>>4)*8..+7]
__global__ __launch_bounds__(256) void repack(const float* __restrict__ img,
                                              const float* __restrict__ txt,
                                              _Float16* __restrict__ Apk,
                                              _Float16* __restrict__ Bpk) {
  int gid = blockIdx.x * 256 + threadIdx.x;
  const float* src;
  _Float16* dst;
  if (gid < AUNITS) {
    int l = gid & 63, g = gid >> 6;
    int s = g % 24; g /= 24;
    int tau = g % 13; int i = g / 13;
    int n = tau * 16 + (l & 15); if (n > 195) n = 195;   // dup-pad rows 196..207
    src = img + (size_t)i * 197 * 768 + (size_t)(n + 1) * 768 + s * 32 + (l >> 4) * 8;
    dst = Apk + (size_t)gid * 8;
  } else {
    int u = gid - AUNITS;
    int l = u & 63, g = u >> 6;
    int ct = g & 3; g >>= 2;
    int s = g % 24; int j = g / 24;
    int m = ct * 16 + (l & 15);
    src = txt + (size_t)j * 65 * 768 + (size_t)(m + 1) * 768 + s * 32 + (l >> 4) * 8;
    dst = Bpk + (size_t)u * 8;
  }
  float4v v0 = *(const float4v*)src;
  float4v v1 = *(const float4v*)(src + 4);
  half8 h;
  h[0] = (_Float16)v0[0]; h[1] = (_Float16)v0[1]; h[2] = (_Float16)v0[2]; h[3] = (_Float16)v0[3];
  h[4] = (_Float16)v1[0]; h[5] = (_Float16)v1[1]; h[6] = (_Float16)v1[2]; h[7] = (_Float16)v1[3];
  *(half8*)dst = h;
}

// ---------- per-(i, j): 1 j per block, 4 waves, 4 BLOCKS PER SIMD ----------
// Empirical law from rounds 0-6: MfmaUtil ~= (independent blocks/SIMD) x duty.
// This design maximizes blocks/SIMD: acc=52 + a 16 + b 16 + addr ~= 115 unified
// regs -> __launch_bounds__(256,4) -> 4 waves/SIMD, each from a DIFFERENT block.
// Wave w owns row tiles {w, w+4, w+8} + column-group w of tile 12.
// A: global->reg depth-1 prefetch, issued AFTER the MFMA cluster (latency hides
//    across the 4 resident blocks). B: DMA to LDS, chunk = 4 K-steps (16 KB),
//    dbuf 32 KB, ONE barrier per chunk with COUNTED vmcnt(16) (16 a-loads are
//    always newer than the wave's 4 chunk-DMAs; never vmcnt(0) mid-loop).
__global__ __launch_bounds__(256, 4) void sim_kernel(const _Float16* __restrict__ Apk,
                                                     const _Float16* __restrict__ Bpk,
                                                     const int* __restrict__ pm,
                                                     const float* __restrict__ ls,
                                                     float* __restrict__ lpi,
                                                     float* __restrict__ lpt) {
  __shared__ _Float16 Bsh[16384];           // [buf2][sc4][ct4][512 halfs] = 32 KB

  const int j = blockIdx.x, i = blockIdx.y;
  const int tid = threadIdx.x;
  const int wave = tid >> 6, lane = tid & 63;
  const int r16 = lane & 15;
  const int lane8 = lane * 8;

  const _Float16* Ai = Apk + (size_t)i * AI_HALFS;
  const _Float16* pA[4];
  pA[0] = Ai + (size_t)(wave)     * 24 * 512 + lane8;
  pA[1] = Ai + (size_t)(wave + 4) * 24 * 512 + lane8;
  pA[2] = Ai + (size_t)(wave + 8) * 24 * 512 + lane8;
  pA[3] = Ai + (size_t)12         * 24 * 512 + lane8;   // tile 12 (all waves)
  const _Float16* Bg = Bpk + (size_t)j * BJ_HALFS;

  // stage chunk cc (K-steps 4cc..4cc+3, 16 pieces x 1KB) : 4 pieces per wave
  auto stage = [&](int cc) {
    const int buf = cc & 1;
#pragma unroll
    for (int r4 = 0; r4 < 4; ++r4) {
      int rr = wave * 4 + r4;               // 0..15 = (sc = rr>>2, ct = rr&3)
      gl_lds16(Bg + (size_t)(4 * cc) * 2048 + rr * 512 + lane8,
               Bsh + buf * 8192 + rr * 512);
    }
  };

  // prologue: stage chunk 0 (4 DMA), then a(0) (4 loads) -> vmcnt(4) == DMA done
  stage(0);
  __builtin_amdgcn_sched_barrier(0);
  half8 af[4];
#pragma unroll
  for (int t = 0; t < 4; ++t) af[t] = *(const half8*)(pA[t]);
  __builtin_amdgcn_sched_barrier(0);
  asm volatile("s_waitcnt vmcnt(4)" ::: "memory");
  __builtin_amdgcn_s_barrier();
  __builtin_amdgcn_sched_barrier(0);

  floatx4 acc[3][4];
  floatx4 acc12 = (floatx4){0.f, 0.f, 0.f, 0.f};
#pragma unroll
  for (int t = 0; t < 3; ++t)
#pragma unroll
    for (int cc = 0; cc < 4; ++cc)
      acc[t][cc] = (floatx4){0.f, 0.f, 0.f, 0.f};

#pragma unroll
  for (int c = 0; c < 6; ++c) {
#pragma unroll
    for (int sc = 0; sc < 4; ++sc) {
      const int s = c * 4 + sc;

      if (sc == 0 && c > 0) {
        // handoff: after this wave's last chunk-DMA, exactly 16 a-loads were
        // issued (4 per step of the previous chunk) -> vmcnt(16) proves all
        // DMA retired. Counted wait + raw barrier; prefetches keep flying.
        asm volatile("s_waitcnt vmcnt(16)" ::: "memory");
        __builtin_amdgcn_s_barrier();
        __builtin_amdgcn_sched_barrier(0);
      }

      // B-frags for THIS step from LDS
      const int base = (c & 1) * 8192 + sc * 2048 + lane8;
      half8 b[4];
#pragma unroll
      for (int cc = 0; cc < 4; ++cc) {
        int ct = (wave + cc) & 3;           // rotated: [0] is this wave's own group
        b[cc] = *(const half8*)(Bsh + base + ct * 512);
      }

      if (sc == 0 && c < 5) {               // issue next chunk's 4 DMAs now;
        stage(c + 1);                       // they fly during 4 steps of compute
        __builtin_amdgcn_sched_barrier(0);
      }

      __builtin_amdgcn_s_setprio(1);
#pragma unroll
      for (int cc = 0; cc < 4; ++cc) {
        acc[0][cc] = __builtin_amdgcn_mfma_f32_16x16x32_f16(af[0], b[cc], acc[0][cc], 0, 0, 0);
        acc[1][cc] = __builtin_amdgcn_mfma_f32_16x16x32_f16(af[1], b[cc], acc[1][cc], 0, 0, 0);
        acc[2][cc] = __builtin_amdgcn_mfma_f32_16x16x32_f16(af[2], b[cc], acc[2][cc], 0, 0, 0);
      }
      acc12 = __builtin_amdgcn_mfma_f32_16x16x32_f16(af[3], b[0], acc12, 0, 0, 0);
      __builtin_amdgcn_s_setprio(0);

      // depth-1 A-prefetch for step s+1, issued AFTER the cluster: its L2
      // latency is hidden by the other 3 resident blocks on this SIMD.
      if (s < 23) {
#pragma unroll
        for (int t = 0; t < 4; ++t) af[t] = *(const half8*)(pA[t] + (s + 1) * 512);
      }
      __builtin_amdgcn_sched_barrier(0);
    }
  }

  // ---------------- epilogue (verified in round 1) ----------------
  const float sgl = ls[0];
  bool msk[4];
  int colc[4];
#pragma unroll
  for (int cc = 0; cc < 4; ++cc) {
    colc[cc] = ((wave + cc) & 3) * 16 + r16;
    msk[cc] = pm[i * 65 + 1 + colc[cc]] != 0;
  }

  float rowsum = 0.f;
  float cmv[4];
#pragma unroll
  for (int t = 0; t < 3; ++t) {
#pragma unroll
    for (int r = 0; r < 4; ++r) {
      float rm = -__builtin_inff();
#pragma unroll
      for (int cc = 0; cc < 4; ++cc) {
        float v = acc[t][cc][r] * sgl;
        rm = fmaxf(rm, msk[cc] ? -__builtin_inff() : v);
      }
#pragma unroll
      for (int off = 1; off < 16; off <<= 1)
        rm = fmaxf(rm, __shfl_xor(rm, off, 64));
      rowsum += rm;
    }
  }
#pragma unroll
  for (int off = 1; off < 64; off <<= 1) rowsum += __shfl_xor(rowsum, off, 64);

  // per-column max over rows 0..191 (unmasked, per reference max_n)
#pragma unroll
  for (int cc = 0; cc < 4; ++cc) {
    float cm = -__builtin_inff();
#pragma unroll
    for (int t = 0; t < 3; ++t)
#pragma unroll
      for (int r = 0; r < 4; ++r)
        cm = fmaxf(cm, acc[t][cc][r] * sgl);
    cm = fmaxf(cm, __shfl_xor(cm, 16, 64));
    cm = fmaxf(cm, __shfl_xor(cm, 32, 64));
    cmv[cc] = cm;
  }

  __syncthreads();                          // all B reads done -> alias Bsh as scratch
  float* colmaxS = (float*)Bsh;             // [4][64]
  float* t12S    = (float*)Bsh + 256;       // [4][64]
  float* wsumS   = (float*)Bsh + 512;       // [4]

  if (lane == 0) wsumS[wave] = rowsum;
  if (lane < 16) {
#pragma unroll
    for (int cc = 0; cc < 4; ++cc) colmaxS[wave * 64 + colc[cc]] = cmv[cc];
#pragma unroll
    for (int r = 0; r < 4; ++r) t12S[r * 64 + wave * 16 + r16] = acc12[r] * sgl;
  }
  __syncthreads();

  if (tid < 64) {
    const int col = lane;
    bool valid = pm[i * 65 + 1 + col] == 0;
    float t0 = t12S[col], t1 = t12S[64 + col], t2 = t12S[128 + col], t3 = t12S[192 + col];
    float v = fmaxf(fmaxf(colmaxS[col], colmaxS[64 + col]),
                    fmaxf(colmaxS[128 + col], colmaxS[192 + col]));
    v = fmaxf(v, fmaxf(fmaxf(t0, t1), fmaxf(t2, t3)));       // full col max (n=0..195)
    float contrib = valid ? v : 0.f;
    float cntv = valid ? 1.f : 0.f;
    float rs0 = valid ? t0 : -__builtin_inff();
    float rs1 = valid ? t1 : -__builtin_inff();
    float rs2 = valid ? t2 : -__builtin_inff();
    float rs3 = valid ? t3 : -__builtin_inff();
#pragma unroll
    for (int off = 1; off < 64; off <<= 1) {
      contrib += __shfl_xor(contrib, off, 64);
      cntv += __shfl_xor(cntv, off, 64);
      rs0 = fmaxf(rs0, __shfl_xor(rs0, off, 64));
      rs1 = fmaxf(rs1, __shfl_xor(rs1, off, 64));
      rs2 = fmaxf(rs2, __shfl_xor(rs2, off, 64));
      rs3 = fmaxf(rs3, __shfl_xor(rs3, off, 64));
    }
    if (lane == 0) {
      lpt[i * 64 + j] = contrib / cntv;
      float wtot = wsumS[0] + wsumS[1] + wsumS[2] + wsumS[3];
      lpi[i * 64 + j] = (wtot * 0.0625f + rs0 + rs1 + rs2 + rs3) / 196.f;
    }
  }
}

// ---------------- CE losses + targets (2 waves: lpi & lpt in parallel) ------
// out layout: [0] loss | [1..4097) lpi | [4097..8193) lpt | [8193..8257) targets
__global__ __launch_bounds__(128) void ce_kernel(float* __restrict__ out) {
  __shared__ float part[2];
  const int tid = threadIdx.x;
  const int t = tid & 63;
  const float* src = (tid < 64) ? (out + 1) : (out + 1 + 4096);

  float mx = -__builtin_inff();
#pragma unroll
  for (int jj = 0; jj < 64; ++jj) mx = fmaxf(mx, src[t * 64 + jj]);
  float se = 0.f;
#pragma unroll
  for (int jj = 0; jj < 64; ++jj) se += __expf(src[t * 64 + jj] - mx);
  float v = (mx + __logf(se)) - src[t * 64 + t];

#pragma unroll
  for (int off = 1; off < 64; off <<= 1) v += __shfl_xor(v, off, 64);
  if (t == 0) part[tid >> 6] = v;
  __syncthreads();
  if (tid == 0) out[0] = 0.5f * (part[0] + part[1]) / 64.f;
  if (tid < 64) out[1 + 8192 + tid] = (float)tid;   // targets = arange(64)
}

extern "C" void kernel_launch(void* const* d_in, const int* in_sizes, int n_in,
                              void* d_out, int out_size, void* d_ws, size_t ws_size,
                              hipStream_t stream) {
  const float* image = (const float*)d_in[0];   // (64,197,768) f32
  const float* text  = (const float*)d_in[1];   // (64,65,768) f32
  const int*   pm    = (const int*)d_in[2];     // (64,65) i32
  const float* ls    = (const float*)d_in[3];   // scalar
  float* out = (float*)d_out;

  _Float16* Apk = (_Float16*)d_ws;              // fragment-tiled image
  _Float16* Bpk = Apk + A_HALFS;                // fragment-tiled text

  repack<<<(AUNITS + TUNITS) / 256, 256, 0, stream>>>(image, text, Apk, Bpk);

  dim3 grid(64, 64);   // x = j (fast): A_i stays L2-hot across consecutive blocks
  sim_kernel<<<grid, 256, 0, stream>>>(Apk, Bpk, pm, ls, out + 1, out + 1 + 4096);
  ce_kernel<<<1, 128, 0, stream>>>(out);
}